// Round 13
// baseline (825.095 us; speedup 1.0000x reference)
//
#include <hip/hip_runtime.h>
#include <math.h>

// VQQuantizer eval, round 13.
// = round 12 with k_selwrite FUSED into k_mfma via split-K-style completion:
// all 8 col-panel blocks of a row-panel run on the same XCD (swizzle), bump a
// per-panel device-scope counter after publishing their stripe top1/2/t3; the
// last block acquires and finalizes the panel's 128 rows (fp64 exact argmax +
// streamed outputs). Store traffic overlaps remaining MFMA compute instead of
// serializing after it. Counters zeroed per launch via hipMemsetAsync.

#define NROWS 32768
#define DDIM  512
#define KCODE 1024
#define MARGIN_COEF 0.017f

typedef __attribute__((address_space(1))) const void gvoid_t;
typedef __attribute__((address_space(3))) void svoid_t;
typedef float f32x4 __attribute__((ext_vector_type(4)));
typedef short bf16x8 __attribute__((ext_vector_type(8)));

__device__ __forceinline__ void gl16(const void* g, void* s) {
  __builtin_amdgcn_global_load_lds((gvoid_t*)g, (svoid_t*)s, 16, 0, 0);
}
// round-to-nearest-even f32 -> bf16 (finite inputs only)
__device__ __forceinline__ unsigned short f2bf(float x) {
  unsigned u = __float_as_uint(x);
  u = u + 0x7fffu + ((u >> 16) & 1u);
  return (unsigned short)(u >> 16);
}

// ------ codebook inverse norms + normalized codebook (f32 of fp64 math) -----
__global__ __launch_bounds__(256) void k_invc(const float* __restrict__ x,
                                              double* __restrict__ invd,
                                              float* __restrict__ invf,
                                              float* __restrict__ cbn) {
  const int lane = threadIdx.x & 63;
  const int row = blockIdx.x * 4 + (threadIdx.x >> 6);
  const float* p = x + (size_t)row * DDIM;
  float4 v0 = *(const float4*)(p + lane * 4);
  float4 v1 = *(const float4*)(p + 256 + lane * 4);
  double s = (double)v0.x * v0.x + (double)v0.y * v0.y + (double)v0.z * v0.z + (double)v0.w * v0.w
           + (double)v1.x * v1.x + (double)v1.y * v1.y + (double)v1.z * v1.z + (double)v1.w * v1.w;
  #pragma unroll
  for (int m = 1; m < 64; m <<= 1) s += __shfl_xor(s, m);
  const double iv = 1.0 / fmax(sqrt(s), 1e-6);
  float4 n0, n1;
  n0.x = (float)((double)v0.x * iv); n0.y = (float)((double)v0.y * iv);
  n0.z = (float)((double)v0.z * iv); n0.w = (float)((double)v0.w * iv);
  n1.x = (float)((double)v1.x * iv); n1.y = (float)((double)v1.y * iv);
  n1.z = (float)((double)v1.z * iv); n1.w = (float)((double)v1.w * iv);
  *(float4*)(cbn + (size_t)row * DDIM + lane * 4) = n0;
  *(float4*)(cbn + (size_t)row * DDIM + 256 + lane * 4) = n1;
  if (lane == 0) {
    invd[row] = iv;
    invf[row] = (float)iv;
  }
}

// ------- prep: bf16-hi fragment-tiled + per-row norm (f32 + f64) ----------
__global__ __launch_bounds__(256) void k_prep(const float* __restrict__ src,
                                              unsigned short* __restrict__ hi,
                                              float* __restrict__ nrmf,
                                              double* __restrict__ nrmd) {
  const int tile = blockIdx.x;
  const int t = threadIdx.x;
  const int r = t >> 4;
  const int l16 = t & 15;
  const float4* s4 = (const float4*)(src + (size_t)tile * 16 * DDIM);
  double ss = 0.0;
  #pragma unroll
  for (int j = 0; j < 8; ++j) {
    const int f4 = r * 128 + l16 + j * 16;
    float4 v = s4[f4];
    ss += (double)v.x * v.x + (double)v.y * v.y + (double)v.z * v.z + (double)v.w * v.w;
    const int k = (l16 + j * 16) * 4;
    const int kc = k >> 5;
    const int l = r | (((k >> 3) & 3) << 4);
    ushort4 h4;
    h4.x = f2bf(v.x); h4.y = f2bf(v.y); h4.z = f2bf(v.z); h4.w = f2bf(v.w);
    *(ushort4*)(hi + (size_t)tile * 8192 + kc * 512 + l * 8 + (k & 7)) = h4;
  }
  #pragma unroll
  for (int m = 1; m < 16; m <<= 1) ss += __shfl_xor(ss, m);
  if (l16 == 0) {
    const double nd = sqrt(ss);
    nrmf[tile * 16 + r] = (float)nd;
    nrmd[tile * 16 + r] = nd;
  }
}

// -------- MFMA scorer + fused completion ------------------------------------
// Swizzle: pr=(bid&7)*32+(bid>>6), pc=(bid>>3)&7. XCD = bid&7 is identical for
// all 8 pc-blocks of a pr -> pcand/pt3 stay in that XCD's L2.
__global__ __launch_bounds__(256) void k_mfma(const unsigned short* __restrict__ AThi,
                                              const unsigned short* __restrict__ BThi,
                                              const float* __restrict__ invcf,
                                              const float* __restrict__ hnormf,
                                              const float* __restrict__ h,
                                              const float* __restrict__ cb,
                                              const float* __restrict__ cbn,
                                              const double* __restrict__ invcd,
                                              const double* __restrict__ hnormd,
                                              float4* __restrict__ pcand,
                                              int* __restrict__ pt3,
                                              int* __restrict__ cnt,
                                              float* __restrict__ out_q,
                                              float* __restrict__ out_ct,
                                              float* __restrict__ out_ch,
                                              float* __restrict__ out_cq,
                                              float* __restrict__ out_idx,
                                              double* __restrict__ lsum) {
  __shared__ bf16x8 lds[2048];   // 2 bufs x {A 512, B 512} slots = 32 KB
  __shared__ int sdone;
  const int tx = threadIdx.x;
  const int bid = blockIdx.x;
  const int pr = (bid & 7) * 32 + (bid >> 6);
  const int pc = (bid >> 3) & 7;
  const int lane = tx & 63;
  const int wid = tx >> 6;
  const int wr = wid >> 1, wc = wid & 1;

  f32x4 acc[4][4];
  #pragma unroll
  for (int m = 0; m < 4; ++m)
    #pragma unroll
    for (int n = 0; n < 4; ++n) acc[m][n] = (f32x4)(0.0f);

  const size_t aA0 = (size_t)(pr * 8 + wid) * 8192 + lane * 8;
  const size_t aA1 = (size_t)(pr * 8 + wid + 4) * 8192 + lane * 8;
  const size_t aB0 = (size_t)(pc * 8 + wid) * 8192 + lane * 8;
  const size_t aB1 = (size_t)(pc * 8 + wid + 4) * 8192 + lane * 8;
  const int slA0 = wid * 64 + lane;
  const int slA1 = (wid + 4) * 64 + lane;
  const int slB0 = 512 + wid * 64 + lane;
  const int slB1 = 512 + (wid + 4) * 64 + lane;

#define STAGE(bufi, kcc)                                   \
  {                                                        \
    bf16x8* base = &lds[(bufi) * 1024];                    \
    const int o_ = (kcc) * 512;                            \
    gl16(AThi + aA0 + o_, base + slA0);                    \
    gl16(AThi + aA1 + o_, base + slA1);                    \
    gl16(BThi + aB0 + o_, base + slB0);                    \
    gl16(BThi + aB1 + o_, base + slB1);                    \
  }

  STAGE(0, 0);
  __syncthreads();

  for (int kc = 0; kc < 16; ++kc) {
    if (kc < 15) STAGE((kc + 1) & 1, kc + 1);
    const bf16x8* L = &lds[(kc & 1) * 1024];
    bf16x8 af[4], bq[4];
    #pragma unroll
    for (int m = 0; m < 4; ++m) af[m] = L[(wr * 4 + m) * 64 + lane];
    #pragma unroll
    for (int n = 0; n < 4; ++n) bq[n] = L[512 + (wc * 4 + n) * 64 + lane];
    #pragma unroll
    for (int m = 0; m < 4; ++m)
      #pragma unroll
      for (int n = 0; n < 4; ++n)
        acc[m][n] = __builtin_amdgcn_mfma_f32_16x16x32_bf16(af[m], bq[n], acc[m][n], 0, 0, 0);
    __syncthreads();
  }
#undef STAGE

  // ---- per-stripe top1/top2/t3 publish ----
  {
    const int q = lane >> 4;
    const int c16 = lane & 15;
    const int rowbase = pr * 128 + wr * 64;
    const int colbase = pc * 128 + wc * 64;
    const int st = colbase >> 6;

    float invn[4];
    #pragma unroll
    for (int n4 = 0; n4 < 4; ++n4) invn[n4] = invcf[colbase + n4 * 16 + c16];

    #pragma unroll
    for (int m = 0; m < 4; ++m) {
      #pragma unroll
      for (int r = 0; r < 4; ++r) {
        const int row = rowbase + m * 16 + q * 4 + r;
        float sv[4];
        #pragma unroll
        for (int n4 = 0; n4 < 4; ++n4) sv[n4] = acc[m][n4][r] * invn[n4];

        float t1 = sv[0]; int i1 = colbase + c16;
        #pragma unroll
        for (int n4 = 1; n4 < 4; ++n4) {
          const int idx = colbase + n4 * 16 + c16;
          if (sv[n4] > t1) { t1 = sv[n4]; i1 = idx; }
        }
        #pragma unroll
        for (int msk = 1; msk < 16; msk <<= 1) {
          float os = __shfl_xor(t1, msk); int oi = __shfl_xor(i1, msk);
          if (os > t1 || (os == t1 && oi < i1)) { t1 = os; i1 = oi; }
        }

        float t2 = -3.4e38f; int i2 = 0x7fffffff;
        #pragma unroll
        for (int n4 = 0; n4 < 4; ++n4) {
          const int idx = colbase + n4 * 16 + c16;
          if (idx != i1 && sv[n4] > t2) { t2 = sv[n4]; i2 = idx; }
        }
        #pragma unroll
        for (int msk = 1; msk < 16; msk <<= 1) {
          float os = __shfl_xor(t2, msk); int oi = __shfl_xor(i2, msk);
          if (os > t2 || (os == t2 && oi < i2)) { t2 = os; i2 = oi; }
        }

        float t3 = -3.4e38f;
        #pragma unroll
        for (int n4 = 0; n4 < 4; ++n4) {
          const int idx = colbase + n4 * 16 + c16;
          if (idx != i1 && idx != i2 && sv[n4] > t3) t3 = sv[n4];
        }
        #pragma unroll
        for (int msk = 1; msk < 16; msk <<= 1)
          t3 = fmaxf(t3, __shfl_xor(t3, msk));

        if (c16 == 0) {
          pcand[(size_t)row * 16 + st] = make_float4(t1, __int_as_float(i1), t2, __int_as_float(i2));
          pt3[(size_t)row * 16 + st] = __float_as_int(t3);
        }
      }
    }
  }

  // ---- completion: last block of this pr finalizes its 128 rows ----
  __threadfence();            // release: publish pcand/pt3 device-wide
  __syncthreads();            // all threads' stores issued before the bump
  if (tx == 0) sdone = atomicAdd(&cnt[pr], 1);
  __syncthreads();
  if (sdone != 7) return;     // not last -> done
  __threadfence();            // acquire: see all 8 blocks' pcand/pt3

  for (int i = 0; i < 32; ++i) {
    const int row = pr * 128 + wid * 32 + i;

    float4 pc4 = make_float4(-3.4e38f, 0.0f, -3.4e38f, 0.0f);
    float t3 = -3.4e38f;
    if (lane < 16) {
      pc4 = pcand[(size_t)row * 16 + lane];
      t3 = __int_as_float(pt3[(size_t)row * 16 + lane]);
    }
    float best = pc4.x;
    #pragma unroll
    for (int m = 1; m < 64; m <<= 1) best = fmaxf(best, __shfl_xor(best, m));
    const float thr = best - MARGIN_COEF * hnormf[row];

    const unsigned long long m1 = __ballot(pc4.x >= thr);
    const unsigned long long m2 = __ballot(pc4.z >= thr);
    const unsigned long long mr = __ballot(t3 >= thr);   // ~never fires

    const float* hrow = h + (size_t)row * DDIM;
    const f32x4 h0 = *(const f32x4*)(hrow + lane * 4);
    const f32x4 h1 = *(const f32x4*)(hrow + 256 + lane * 4);

    double bs = -1e300; int bi = 0x7fffffff;
    const int i1 = __float_as_int(pc4.y);
    const int i2 = __float_as_int(pc4.w);

    #define RESCORE(codeexpr)                                                 \
      {                                                                       \
        const int code = (codeexpr);                                          \
        const float* cp = cb + (size_t)code * DDIM;                           \
        const f32x4 c0 = *(const f32x4*)(cp + lane * 4);                      \
        const f32x4 c1 = *(const f32x4*)(cp + 256 + lane * 4);                \
        double p = (double)h0.x * c0.x + (double)h0.y * c0.y                  \
                 + (double)h0.z * c0.z + (double)h0.w * c0.w                  \
                 + (double)h1.x * c1.x + (double)h1.y * c1.y                  \
                 + (double)h1.z * c1.z + (double)h1.w * c1.w;                 \
        _Pragma("unroll")                                                     \
        for (int m = 1; m < 64; m <<= 1) p += __shfl_xor(p, m);               \
        const double sc = p * invcd[code];                                    \
        if (sc > bs || (sc == bs && code < bi)) { bs = sc; bi = code; }       \
      }

    for (unsigned long long mm = m1; mm; mm &= mm - 1)
      RESCORE(__shfl(i1, __builtin_ctzll(mm)));
    for (unsigned long long mm = m2; mm; mm &= mm - 1)
      RESCORE(__shfl(i2, __builtin_ctzll(mm)));
    for (unsigned long long mm = mr; mm; mm &= mm - 1) {
      const int st = __builtin_ctzll(mm);
      for (int j = 0; j < 64; ++j) RESCORE(st * 64 + j);
    }
    #undef RESCORE

    if (lane == 0) out_idx[row] = (float)bi;

    {
      float* qrow = out_q + (size_t)row * KCODE;
      #pragma unroll
      for (int p = 0; p < 4; ++p) {
        const int col = p * 256 + lane * 4;
        f32x4 qv;
        qv.x = (col + 0 == bi) ? 1.0f : 0.0f;
        qv.y = (col + 1 == bi) ? 1.0f : 0.0f;
        qv.z = (col + 2 == bi) ? 1.0f : 0.0f;
        qv.w = (col + 3 == bi) ? 1.0f : 0.0f;
        __builtin_nontemporal_store(qv, (f32x4*)(qrow + col));
      }
    }

    const double ih = 1.0 / fmax(hnormd[row], 1e-6);
    const float* crow = cbn + (size_t)bi * DDIM;
    const f32x4 c0 = *(const f32x4*)(crow + lane * 4);
    const f32x4 c1 = *(const f32x4*)(crow + 256 + lane * 4);

    const size_t ro0 = (size_t)row * DDIM + lane * 4;
    const size_t ro1 = ro0 + 256;
    __builtin_nontemporal_store(c0, (f32x4*)(out_ct + ro0));
    __builtin_nontemporal_store(c1, (f32x4*)(out_ct + ro1));
    __builtin_nontemporal_store(c0, (f32x4*)(out_ch + ro0));
    __builtin_nontemporal_store(c1, (f32x4*)(out_ch + ro1));
    __builtin_nontemporal_store(c0, (f32x4*)(out_cq + ro0));
    __builtin_nontemporal_store(c1, (f32x4*)(out_cq + ro1));

    double ls = 0.0, e;
    e = (double)h0.x * ih - (double)c0.x; ls += e * e;
    e = (double)h0.y * ih - (double)c0.y; ls += e * e;
    e = (double)h0.z * ih - (double)c0.z; ls += e * e;
    e = (double)h0.w * ih - (double)c0.w; ls += e * e;
    e = (double)h1.x * ih - (double)c1.x; ls += e * e;
    e = (double)h1.y * ih - (double)c1.y; ls += e * e;
    e = (double)h1.z * ih - (double)c1.z; ls += e * e;
    e = (double)h1.w * ih - (double)c1.w; ls += e * e;
    #pragma unroll
    for (int m = 1; m < 64; m <<= 1) ls += __shfl_xor(ls, m);
    if (lane == 0) lsum[row] = ls;
  }
}

__global__ __launch_bounds__(256) void k_loss(const double* __restrict__ lsum,
                                              float* __restrict__ out_loss) {
  const int tx = threadIdx.x;
  double s = 0.0;
  for (int i = tx; i < NROWS; i += 256) s += lsum[i];
  #pragma unroll
  for (int m = 1; m < 64; m <<= 1) s += __shfl_xor(s, m);
  __shared__ double sh[4];
  if ((tx & 63) == 0) sh[tx >> 6] = s;
  __syncthreads();
  if (tx == 0)
    out_loss[0] = (float)(1.25 * (sh[0] + sh[1] + sh[2] + sh[3]) / ((double)NROWS * (double)DDIM));
}

extern "C" void kernel_launch(void* const* d_in, const int* in_sizes, int n_in,
                              void* d_out, int out_size, void* d_ws, size_t ws_size,
                              hipStream_t stream) {
  const float* h = (const float*)d_in[0];
  const float* cb = (const float*)d_in[1];

  float* out = (float*)d_out;
  float* out_q    = out;
  float* out_ct   = out + 33554432;
  float* out_ch   = out + 50331648;
  float* out_cq   = out + 67108864;
  float* out_loss = out + 83886080;
  float* out_idx  = out + 83886081;

  char* ws = (char*)d_ws;
  unsigned short* AThi = (unsigned short*)(ws);               // 32 MB
  unsigned short* BThi = (unsigned short*)(ws + 33554432);    // 1 MB
  double* invcd  = (double*)(ws + 34603008);                  // 8 KB
  float*  invcf  = (float*)(ws + 34611200);                   // 4 KB
  float*  hnormf = (float*)(ws + 34615296);                   // 128 KB
  float*  cbnrmf = (float*)(ws + 34746368);                   // 4 KB (sink)
  float*  cbn    = (float*)(ws + 34750464);                   // 2 MB
  float4* pcand  = (float4*)(ws + 36847616);                  // 8 MB
  int*    pt3    = (int*)(ws + 45236224);                     // 2 MB
  double* lsum   = (double*)(ws + 47333376);                  // 256 KB
  double* hnormd = (double*)(ws + 47595520);                  // 256 KB
  double* cbnrmd = (double*)(ws + 47857664);                  // 8 KB (sink)
  int*    cnt    = (int*)(ws + 47865856);                     // 1 KB (256 ints)

  hipMemsetAsync(cnt, 0, 1024, stream);
  k_invc<<<KCODE / 4, 256, 0, stream>>>(cb, invcd, invcf, cbn);
  k_prep<<<NROWS / 16, 256, 0, stream>>>(h, AThi, hnormf, hnormd);
  k_prep<<<KCODE / 16, 256, 0, stream>>>(cb, BThi, cbnrmf, cbnrmd);
  k_mfma<<<2048, 256, 0, stream>>>(AThi, BThi, invcf, hnormf,
                                   h, cb, cbn, invcd, hnormd,
                                   pcand, pt3, cnt,
                                   out_q, out_ct, out_ch, out_cq,
                                   out_idx, lsum);
  k_loss<<<1, 256, 0, stream>>>(lsum, out_loss);
}

// Round 14
// 291.573 us; speedup vs baseline: 2.8298x; 2.8298x over previous
//
#include <hip/hip_runtime.h>
#include <math.h>

// VQQuantizer eval, round 14 = round 12 (274us, known good) with ONE k_mfma
// parameter change: tile 256x128 (was 128x128), 4 waves, wave = 64x128 =
// acc[4][8], BK=32 double-buffer + __syncthreads (sync structure unchanged).
// 32 MFMA per wave per barrier (2x amortization of the per-chunk drain),
// staged bytes 512->384 MB, grid 1024. Round-13's completion fusion reverted
// (it cut selwrite parallelism 30x -> 3x regression).

#define NROWS 32768
#define DDIM  512
#define KCODE 1024
#define MARGIN_COEF 0.017f

typedef __attribute__((address_space(1))) const void gvoid_t;
typedef __attribute__((address_space(3))) void svoid_t;
typedef float f32x4 __attribute__((ext_vector_type(4)));
typedef short bf16x8 __attribute__((ext_vector_type(8)));

__device__ __forceinline__ void gl16(const void* g, void* s) {
  __builtin_amdgcn_global_load_lds((gvoid_t*)g, (svoid_t*)s, 16, 0, 0);
}
// round-to-nearest-even f32 -> bf16 (finite inputs only)
__device__ __forceinline__ unsigned short f2bf(float x) {
  unsigned u = __float_as_uint(x);
  u = u + 0x7fffu + ((u >> 16) & 1u);
  return (unsigned short)(u >> 16);
}

// ------ codebook inverse norms + normalized codebook (f32 of fp64 math) -----
__global__ __launch_bounds__(256) void k_invc(const float* __restrict__ x,
                                              double* __restrict__ invd,
                                              float* __restrict__ invf,
                                              float* __restrict__ cbn) {
  const int lane = threadIdx.x & 63;
  const int row = blockIdx.x * 4 + (threadIdx.x >> 6);
  const float* p = x + (size_t)row * DDIM;
  float4 v0 = *(const float4*)(p + lane * 4);
  float4 v1 = *(const float4*)(p + 256 + lane * 4);
  double s = (double)v0.x * v0.x + (double)v0.y * v0.y + (double)v0.z * v0.z + (double)v0.w * v0.w
           + (double)v1.x * v1.x + (double)v1.y * v1.y + (double)v1.z * v1.z + (double)v1.w * v1.w;
  #pragma unroll
  for (int m = 1; m < 64; m <<= 1) s += __shfl_xor(s, m);
  const double iv = 1.0 / fmax(sqrt(s), 1e-6);
  float4 n0, n1;
  n0.x = (float)((double)v0.x * iv); n0.y = (float)((double)v0.y * iv);
  n0.z = (float)((double)v0.z * iv); n0.w = (float)((double)v0.w * iv);
  n1.x = (float)((double)v1.x * iv); n1.y = (float)((double)v1.y * iv);
  n1.z = (float)((double)v1.z * iv); n1.w = (float)((double)v1.w * iv);
  *(float4*)(cbn + (size_t)row * DDIM + lane * 4) = n0;
  *(float4*)(cbn + (size_t)row * DDIM + 256 + lane * 4) = n1;
  if (lane == 0) {
    invd[row] = iv;
    invf[row] = (float)iv;
  }
}

// ------- prep: bf16-hi fragment-tiled + per-row norm (f32 + f64) ----------
__global__ __launch_bounds__(256) void k_prep(const float* __restrict__ src,
                                              unsigned short* __restrict__ hi,
                                              float* __restrict__ nrmf,
                                              double* __restrict__ nrmd) {
  const int tile = blockIdx.x;
  const int t = threadIdx.x;
  const int r = t >> 4;
  const int l16 = t & 15;
  const float4* s4 = (const float4*)(src + (size_t)tile * 16 * DDIM);
  double ss = 0.0;
  #pragma unroll
  for (int j = 0; j < 8; ++j) {
    const int f4 = r * 128 + l16 + j * 16;
    float4 v = s4[f4];
    ss += (double)v.x * v.x + (double)v.y * v.y + (double)v.z * v.z + (double)v.w * v.w;
    const int k = (l16 + j * 16) * 4;
    const int kc = k >> 5;
    const int l = r | (((k >> 3) & 3) << 4);
    ushort4 h4;
    h4.x = f2bf(v.x); h4.y = f2bf(v.y); h4.z = f2bf(v.z); h4.w = f2bf(v.w);
    *(ushort4*)(hi + (size_t)tile * 8192 + kc * 512 + l * 8 + (k & 7)) = h4;
  }
  #pragma unroll
  for (int m = 1; m < 16; m <<= 1) ss += __shfl_xor(ss, m);
  if (l16 == 0) {
    const double nd = sqrt(ss);
    nrmf[tile * 16 + r] = (float)nd;
    nrmd[tile * 16 + r] = nd;
  }
}

// -------- MFMA scorer: 256x128 tile, hi-only, BK=32, dbuf + syncthreads ----
// Swizzle: pr=(bid&7)*16+(bid>>6), pc=(bid>>3)&7 (bijective over 1024);
// XCD = bid&7 identical for all 8 pc-blocks of a pr (A-panel L2 locality).
// 4 waves; wave wid owns rows wid*64..+64 x all 128 cols: acc[4][8].
__global__ __launch_bounds__(256) void k_mfma(const unsigned short* __restrict__ AThi,
                                              const unsigned short* __restrict__ BThi,
                                              const float* __restrict__ invcf,
                                              const float* __restrict__ hnormf,
                                              float4* __restrict__ pcand,
                                              int* __restrict__ pt3) {
  __shared__ bf16x8 lds[3072];   // 2 bufs x {A 1024, B 512} slots = 48 KB
  const int tx = threadIdx.x;
  const int bid = blockIdx.x;
  const int pr = (bid & 7) * 16 + (bid >> 6);   // 0..127 (256-row panels)
  const int pc = (bid >> 3) & 7;                // 0..7   (128-col panels)
  const int lane = tx & 63;
  const int wid = tx >> 6;

  f32x4 acc[4][8];
  #pragma unroll
  for (int m = 0; m < 4; ++m)
    #pragma unroll
    for (int n = 0; n < 8; ++n) acc[m][n] = (f32x4)(0.0f);

  // staging: A 1024 slots (4/thread), B 512 slots (2/thread)
  const int sA0 = tx, sA1 = tx + 256, sA2 = tx + 512, sA3 = tx + 768;
  const int sB0 = tx, sB1 = tx + 256;
  const size_t aA0 = (size_t)(pr * 16 + (sA0 >> 6)) * 8192 + (sA0 & 63) * 8;
  const size_t aA1 = (size_t)(pr * 16 + (sA1 >> 6)) * 8192 + (sA1 & 63) * 8;
  const size_t aA2 = (size_t)(pr * 16 + (sA2 >> 6)) * 8192 + (sA2 & 63) * 8;
  const size_t aA3 = (size_t)(pr * 16 + (sA3 >> 6)) * 8192 + (sA3 & 63) * 8;
  const size_t aB0 = (size_t)(pc * 8 + (sB0 >> 6)) * 8192 + (sB0 & 63) * 8;
  const size_t aB1 = (size_t)(pc * 8 + (sB1 >> 6)) * 8192 + (sB1 & 63) * 8;

#define STAGE(bufi, kcc)                                   \
  {                                                        \
    bf16x8* base = &lds[(bufi) * 1536];                    \
    const int o_ = (kcc) * 512;                            \
    gl16(AThi + aA0 + o_, base + sA0);                     \
    gl16(AThi + aA1 + o_, base + sA1);                     \
    gl16(AThi + aA2 + o_, base + sA2);                     \
    gl16(AThi + aA3 + o_, base + sA3);                     \
    gl16(BThi + aB0 + o_, base + 1024 + sB0);              \
    gl16(BThi + aB1 + o_, base + 1024 + sB1);              \
  }

  STAGE(0, 0);
  __syncthreads();   // chunk 0 landed (compiler drains vmcnt before barrier)

  for (int kc = 0; kc < 16; ++kc) {
    if (kc < 15) STAGE((kc + 1) & 1, kc + 1);   // prefetch next chunk
    const bf16x8* L = &lds[(kc & 1) * 1536];
    bf16x8 af[4], bq[8];
    #pragma unroll
    for (int m = 0; m < 4; ++m) af[m] = L[(wid * 4 + m) * 64 + lane];
    #pragma unroll
    for (int n = 0; n < 8; ++n) bq[n] = L[1024 + n * 64 + lane];
    #pragma unroll
    for (int m = 0; m < 4; ++m)
      #pragma unroll
      for (int n = 0; n < 8; ++n)
        acc[m][n] = __builtin_amdgcn_mfma_f32_16x16x32_bf16(af[m], bq[n], acc[m][n], 0, 0, 0);
    __syncthreads();   // prefetch landed + all waves done reading this buf
  }
#undef STAGE

  // ---- epilogue: per-row top1/top2/t3 over two 64-col stripes ----
  const int q = lane >> 4;
  const int c16 = lane & 15;
  const int rowbase = pr * 256 + wid * 64;

  #pragma unroll
  for (int hn = 0; hn < 2; ++hn) {
    const int colbase = pc * 128 + hn * 64;
    const int st = colbase >> 6;
    float invn[4];
    #pragma unroll
    for (int n4 = 0; n4 < 4; ++n4) invn[n4] = invcf[colbase + n4 * 16 + c16];

    #pragma unroll
    for (int m = 0; m < 4; ++m) {
      #pragma unroll
      for (int r = 0; r < 4; ++r) {
        const int row = rowbase + m * 16 + q * 4 + r;
        float sv[4];
        #pragma unroll
        for (int n4 = 0; n4 < 4; ++n4) sv[n4] = acc[m][hn * 4 + n4][r] * invn[n4];

        // top1 (lowest index on ties)
        float t1 = sv[0]; int i1 = colbase + c16;
        #pragma unroll
        for (int n4 = 1; n4 < 4; ++n4) {
          const int idx = colbase + n4 * 16 + c16;
          if (sv[n4] > t1) { t1 = sv[n4]; i1 = idx; }
        }
        #pragma unroll
        for (int msk = 1; msk < 16; msk <<= 1) {
          float os = __shfl_xor(t1, msk); int oi = __shfl_xor(i1, msk);
          if (os > t1 || (os == t1 && oi < i1)) { t1 = os; i1 = oi; }
        }

        // top2 (best excluding i1)
        float t2 = -3.4e38f; int i2 = 0x7fffffff;
        #pragma unroll
        for (int n4 = 0; n4 < 4; ++n4) {
          const int idx = colbase + n4 * 16 + c16;
          if (idx != i1 && sv[n4] > t2) { t2 = sv[n4]; i2 = idx; }
        }
        #pragma unroll
        for (int msk = 1; msk < 16; msk <<= 1) {
          float os = __shfl_xor(t2, msk); int oi = __shfl_xor(i2, msk);
          if (os > t2 || (os == t2 && oi < i2)) { t2 = os; i2 = oi; }
        }

        // top3 VALUE (rescan trigger)
        float t3 = -3.4e38f;
        #pragma unroll
        for (int n4 = 0; n4 < 4; ++n4) {
          const int idx = colbase + n4 * 16 + c16;
          if (idx != i1 && idx != i2 && sv[n4] > t3) t3 = sv[n4];
        }
        #pragma unroll
        for (int msk = 1; msk < 16; msk <<= 1)
          t3 = fmaxf(t3, __shfl_xor(t3, msk));

        if (c16 == 0) {
          pcand[(size_t)row * 16 + st] = make_float4(t1, __int_as_float(i1), t2, __int_as_float(i2));
          pt3[(size_t)row * 16 + st] = __float_as_int(t3);
        }
      }
    }
  }
}

// ------ fused select+write: one wave per row (round 12, unchanged) ------
__global__ __launch_bounds__(256) void k_selwrite(const float* __restrict__ h,
                                                  const float* __restrict__ cb,
                                                  const float* __restrict__ cbn,
                                                  const double* __restrict__ invcd,
                                                  const double* __restrict__ hnormd,
                                                  const float* __restrict__ hnormf,
                                                  const float4* __restrict__ pcand,
                                                  const int* __restrict__ pt3,
                                                  float* __restrict__ out_q,
                                                  float* __restrict__ out_ct,
                                                  float* __restrict__ out_ch,
                                                  float* __restrict__ out_cq,
                                                  float* __restrict__ out_idx,
                                                  double* __restrict__ lsum) {
  const int lane = threadIdx.x & 63;
  const int row = blockIdx.x * 4 + (threadIdx.x >> 6);

  float4 pc4 = make_float4(-3.4e38f, 0.0f, -3.4e38f, 0.0f);
  float t3 = -3.4e38f;
  if (lane < 16) {
    pc4 = pcand[(size_t)row * 16 + lane];
    t3 = __int_as_float(pt3[(size_t)row * 16 + lane]);
  }
  float best = pc4.x;
  #pragma unroll
  for (int m = 1; m < 64; m <<= 1) best = fmaxf(best, __shfl_xor(best, m));
  const float thr = best - MARGIN_COEF * hnormf[row];

  const unsigned long long m1 = __ballot(pc4.x >= thr);
  const unsigned long long m2 = __ballot(pc4.z >= thr);
  const unsigned long long mr = __ballot(t3 >= thr);   // ~never fires

  const float* hrow = h + (size_t)row * DDIM;
  const f32x4 h0 = *(const f32x4*)(hrow + lane * 4);
  const f32x4 h1 = *(const f32x4*)(hrow + 256 + lane * 4);

  double bs = -1e300; int bi = 0x7fffffff;
  const int i1 = __float_as_int(pc4.y);
  const int i2 = __float_as_int(pc4.w);

  #define RESCORE(codeexpr)                                                   \
    {                                                                         \
      const int code = (codeexpr);                                            \
      const float* cp = cb + (size_t)code * DDIM;                             \
      const f32x4 c0 = *(const f32x4*)(cp + lane * 4);                        \
      const f32x4 c1 = *(const f32x4*)(cp + 256 + lane * 4);                  \
      double p = (double)h0.x * c0.x + (double)h0.y * c0.y                    \
               + (double)h0.z * c0.z + (double)h0.w * c0.w                    \
               + (double)h1.x * c1.x + (double)h1.y * c1.y                    \
               + (double)h1.z * c1.z + (double)h1.w * c1.w;                   \
      _Pragma("unroll")                                                       \
      for (int m = 1; m < 64; m <<= 1) p += __shfl_xor(p, m);                 \
      const double sc = p * invcd[code];                                      \
      if (sc > bs || (sc == bs && code < bi)) { bs = sc; bi = code; }         \
    }

  for (unsigned long long mm = m1; mm; mm &= mm - 1)
    RESCORE(__shfl(i1, __builtin_ctzll(mm)));
  for (unsigned long long mm = m2; mm; mm &= mm - 1)
    RESCORE(__shfl(i2, __builtin_ctzll(mm)));
  for (unsigned long long mm = mr; mm; mm &= mm - 1) {
    const int st = __builtin_ctzll(mm);
    for (int j = 0; j < 64; ++j) RESCORE(st * 64 + j);
  }
  #undef RESCORE

  if (lane == 0) out_idx[row] = (float)bi;

  {
    float* qrow = out_q + (size_t)row * KCODE;
    #pragma unroll
    for (int p = 0; p < 4; ++p) {
      const int col = p * 256 + lane * 4;
      f32x4 qv;
      qv.x = (col + 0 == bi) ? 1.0f : 0.0f;
      qv.y = (col + 1 == bi) ? 1.0f : 0.0f;
      qv.z = (col + 2 == bi) ? 1.0f : 0.0f;
      qv.w = (col + 3 == bi) ? 1.0f : 0.0f;
      __builtin_nontemporal_store(qv, (f32x4*)(qrow + col));
    }
  }

  const double ih = 1.0 / fmax(hnormd[row], 1e-6);
  const float* crow = cbn + (size_t)bi * DDIM;
  const f32x4 c0 = *(const f32x4*)(crow + lane * 4);
  const f32x4 c1 = *(const f32x4*)(crow + 256 + lane * 4);

  const size_t ro0 = (size_t)row * DDIM + lane * 4;
  const size_t ro1 = ro0 + 256;
  __builtin_nontemporal_store(c0, (f32x4*)(out_ct + ro0));
  __builtin_nontemporal_store(c1, (f32x4*)(out_ct + ro1));
  __builtin_nontemporal_store(c0, (f32x4*)(out_ch + ro0));
  __builtin_nontemporal_store(c1, (f32x4*)(out_ch + ro1));
  __builtin_nontemporal_store(c0, (f32x4*)(out_cq + ro0));
  __builtin_nontemporal_store(c1, (f32x4*)(out_cq + ro1));

  double ls = 0.0, e;
  e = (double)h0.x * ih - (double)c0.x; ls += e * e;
  e = (double)h0.y * ih - (double)c0.y; ls += e * e;
  e = (double)h0.z * ih - (double)c0.z; ls += e * e;
  e = (double)h0.w * ih - (double)c0.w; ls += e * e;
  e = (double)h1.x * ih - (double)c1.x; ls += e * e;
  e = (double)h1.y * ih - (double)c1.y; ls += e * e;
  e = (double)h1.z * ih - (double)c1.z; ls += e * e;
  e = (double)h1.w * ih - (double)c1.w; ls += e * e;
  #pragma unroll
  for (int m = 1; m < 64; m <<= 1) ls += __shfl_xor(ls, m);
  if (lane == 0) lsum[row] = ls;
}

__global__ __launch_bounds__(256) void k_loss(const double* __restrict__ lsum,
                                              float* __restrict__ out_loss) {
  const int tx = threadIdx.x;
  double s = 0.0;
  for (int i = tx; i < NROWS; i += 256) s += lsum[i];
  #pragma unroll
  for (int m = 1; m < 64; m <<= 1) s += __shfl_xor(s, m);
  __shared__ double sh[4];
  if ((tx & 63) == 0) sh[tx >> 6] = s;
  __syncthreads();
  if (tx == 0)
    out_loss[0] = (float)(1.25 * (sh[0] + sh[1] + sh[2] + sh[3]) / ((double)NROWS * (double)DDIM));
}

extern "C" void kernel_launch(void* const* d_in, const int* in_sizes, int n_in,
                              void* d_out, int out_size, void* d_ws, size_t ws_size,
                              hipStream_t stream) {
  const float* h = (const float*)d_in[0];
  const float* cb = (const float*)d_in[1];

  float* out = (float*)d_out;
  float* out_q    = out;
  float* out_ct   = out + 33554432;
  float* out_ch   = out + 50331648;
  float* out_cq   = out + 67108864;
  float* out_loss = out + 83886080;
  float* out_idx  = out + 83886081;

  char* ws = (char*)d_ws;
  unsigned short* AThi = (unsigned short*)(ws);               // 32 MB
  unsigned short* BThi = (unsigned short*)(ws + 33554432);    // 1 MB
  double* invcd  = (double*)(ws + 34603008);                  // 8 KB
  float*  invcf  = (float*)(ws + 34611200);                   // 4 KB
  float*  hnormf = (float*)(ws + 34615296);                   // 128 KB
  float*  cbnrmf = (float*)(ws + 34746368);                   // 4 KB (sink)
  float*  cbn    = (float*)(ws + 34750464);                   // 2 MB
  float4* pcand  = (float4*)(ws + 36847616);                  // 8 MB
  int*    pt3    = (int*)(ws + 45236224);                     // 2 MB
  double* lsum   = (double*)(ws + 47333376);                  // 256 KB
  double* hnormd = (double*)(ws + 47595520);                  // 256 KB
  double* cbnrmd = (double*)(ws + 47857664);                  // 8 KB (sink)

  k_invc<<<KCODE / 4, 256, 0, stream>>>(cb, invcd, invcf, cbn);
  k_prep<<<NROWS / 16, 256, 0, stream>>>(h, AThi, hnormf, hnormd);
  k_prep<<<KCODE / 16, 256, 0, stream>>>(cb, BThi, cbnrmf, cbnrmd);
  k_mfma<<<1024, 256, 0, stream>>>(AThi, BThi, invcf, hnormf, pcand, pt3);
  k_selwrite<<<NROWS / 4, 256, 0, stream>>>(h, cb, cbn, invcd, hnormd, hnormf,
                                            pcand, pt3,
                                            out_q, out_ct, out_ch, out_cq,
                                            out_idx, lsum);
  k_loss<<<1, 256, 0, stream>>>(lsum, out_loss);
}

// Round 15
// 275.894 us; speedup vs baseline: 2.9906x; 1.0568x over previous
//
#include <hip/hip_runtime.h>
#include <math.h>

// VQQuantizer eval, round 15 = round 12 verbatim (the measured optimum, 274us).
// Round-13 (completion fusion, 3x regression) and round-14 (256x128 tile,
// +17us) both reverted. Exactness machinery: hi-only bf16 MFMA scorer,
// margin 0.017*||h|| >= 2x bf16 truncation error bound, per-stripe
// top1/top2 + t3 rescan trigger, fp64 candidate rescoring -> argmax matches
// the float64 numpy reference exactly.

#define NROWS 32768
#define DDIM  512
#define KCODE 1024
#define MARGIN_COEF 0.017f

typedef __attribute__((address_space(1))) const void gvoid_t;
typedef __attribute__((address_space(3))) void svoid_t;
typedef float f32x4 __attribute__((ext_vector_type(4)));
typedef short bf16x8 __attribute__((ext_vector_type(8)));

__device__ __forceinline__ void gl16(const void* g, void* s) {
  __builtin_amdgcn_global_load_lds((gvoid_t*)g, (svoid_t*)s, 16, 0, 0);
}
// round-to-nearest-even f32 -> bf16 (finite inputs only)
__device__ __forceinline__ unsigned short f2bf(float x) {
  unsigned u = __float_as_uint(x);
  u = u + 0x7fffu + ((u >> 16) & 1u);
  return (unsigned short)(u >> 16);
}

// ------ codebook inverse norms + normalized codebook (f32 of fp64 math) -----
__global__ __launch_bounds__(256) void k_invc(const float* __restrict__ x,
                                              double* __restrict__ invd,
                                              float* __restrict__ invf,
                                              float* __restrict__ cbn) {
  const int lane = threadIdx.x & 63;
  const int row = blockIdx.x * 4 + (threadIdx.x >> 6);
  const float* p = x + (size_t)row * DDIM;
  float4 v0 = *(const float4*)(p + lane * 4);
  float4 v1 = *(const float4*)(p + 256 + lane * 4);
  double s = (double)v0.x * v0.x + (double)v0.y * v0.y + (double)v0.z * v0.z + (double)v0.w * v0.w
           + (double)v1.x * v1.x + (double)v1.y * v1.y + (double)v1.z * v1.z + (double)v1.w * v1.w;
  #pragma unroll
  for (int m = 1; m < 64; m <<= 1) s += __shfl_xor(s, m);
  const double iv = 1.0 / fmax(sqrt(s), 1e-6);
  float4 n0, n1;
  n0.x = (float)((double)v0.x * iv); n0.y = (float)((double)v0.y * iv);
  n0.z = (float)((double)v0.z * iv); n0.w = (float)((double)v0.w * iv);
  n1.x = (float)((double)v1.x * iv); n1.y = (float)((double)v1.y * iv);
  n1.z = (float)((double)v1.z * iv); n1.w = (float)((double)v1.w * iv);
  *(float4*)(cbn + (size_t)row * DDIM + lane * 4) = n0;
  *(float4*)(cbn + (size_t)row * DDIM + 256 + lane * 4) = n1;
  if (lane == 0) {
    invd[row] = iv;
    invf[row] = (float)iv;
  }
}

// ------- prep: bf16-hi fragment-tiled + per-row norm (f32 + f64) ----------
__global__ __launch_bounds__(256) void k_prep(const float* __restrict__ src,
                                              unsigned short* __restrict__ hi,
                                              float* __restrict__ nrmf,
                                              double* __restrict__ nrmd) {
  const int tile = blockIdx.x;
  const int t = threadIdx.x;
  const int r = t >> 4;
  const int l16 = t & 15;
  const float4* s4 = (const float4*)(src + (size_t)tile * 16 * DDIM);
  double ss = 0.0;
  #pragma unroll
  for (int j = 0; j < 8; ++j) {
    const int f4 = r * 128 + l16 + j * 16;
    float4 v = s4[f4];
    ss += (double)v.x * v.x + (double)v.y * v.y + (double)v.z * v.z + (double)v.w * v.w;
    const int k = (l16 + j * 16) * 4;
    const int kc = k >> 5;
    const int l = r | (((k >> 3) & 3) << 4);
    ushort4 h4;
    h4.x = f2bf(v.x); h4.y = f2bf(v.y); h4.z = f2bf(v.z); h4.w = f2bf(v.w);
    *(ushort4*)(hi + (size_t)tile * 8192 + kc * 512 + l * 8 + (k & 7)) = h4;
  }
  #pragma unroll
  for (int m = 1; m < 16; m <<= 1) ss += __shfl_xor(ss, m);
  if (l16 == 0) {
    const double nd = sqrt(ss);
    nrmf[tile * 16 + r] = (float)nd;
    nrmd[tile * 16 + r] = nd;
  }
}

// -------- MFMA scorer: 128x128 tile, hi-only, BK=32, dbuf + syncthreads ----
// Swizzle: pr=(bid&7)*32+(bid>>6), pc=(bid>>3)&7 (bijective over 2048);
// XCD = bid&7 identical for all 8 pc-blocks of a pr (A-panel L2 locality).
__global__ __launch_bounds__(256) void k_mfma(const unsigned short* __restrict__ AThi,
                                              const unsigned short* __restrict__ BThi,
                                              const float* __restrict__ invcf,
                                              const float* __restrict__ hnormf,
                                              float4* __restrict__ pcand,
                                              int* __restrict__ pt3) {
  __shared__ bf16x8 lds[2048];   // 2 bufs x {A 512, B 512} slots = 32 KB
  const int tx = threadIdx.x;
  const int bid = blockIdx.x;
  const int pr = (bid & 7) * 32 + (bid >> 6);
  const int pc = (bid >> 3) & 7;
  const int lane = tx & 63;
  const int wid = tx >> 6;
  const int wr = wid >> 1, wc = wid & 1;

  f32x4 acc[4][4];
  #pragma unroll
  for (int m = 0; m < 4; ++m)
    #pragma unroll
    for (int n = 0; n < 4; ++n) acc[m][n] = (f32x4)(0.0f);

  const size_t aA0 = (size_t)(pr * 8 + wid) * 8192 + lane * 8;
  const size_t aA1 = (size_t)(pr * 8 + wid + 4) * 8192 + lane * 8;
  const size_t aB0 = (size_t)(pc * 8 + wid) * 8192 + lane * 8;
  const size_t aB1 = (size_t)(pc * 8 + wid + 4) * 8192 + lane * 8;
  const int slA0 = wid * 64 + lane;
  const int slA1 = (wid + 4) * 64 + lane;
  const int slB0 = 512 + wid * 64 + lane;
  const int slB1 = 512 + (wid + 4) * 64 + lane;

#define STAGE(bufi, kcc)                                   \
  {                                                        \
    bf16x8* base = &lds[(bufi) * 1024];                    \
    const int o_ = (kcc) * 512;                            \
    gl16(AThi + aA0 + o_, base + slA0);                    \
    gl16(AThi + aA1 + o_, base + slA1);                    \
    gl16(BThi + aB0 + o_, base + slB0);                    \
    gl16(BThi + aB1 + o_, base + slB1);                    \
  }

  STAGE(0, 0);
  __syncthreads();

  for (int kc = 0; kc < 16; ++kc) {
    if (kc < 15) STAGE((kc + 1) & 1, kc + 1);
    const bf16x8* L = &lds[(kc & 1) * 1024];
    bf16x8 af[4], bq[4];
    #pragma unroll
    for (int m = 0; m < 4; ++m) af[m] = L[(wr * 4 + m) * 64 + lane];
    #pragma unroll
    for (int n = 0; n < 4; ++n) bq[n] = L[512 + (wc * 4 + n) * 64 + lane];
    #pragma unroll
    for (int m = 0; m < 4; ++m)
      #pragma unroll
      for (int n = 0; n < 4; ++n)
        acc[m][n] = __builtin_amdgcn_mfma_f32_16x16x32_bf16(af[m], bq[n], acc[m][n], 0, 0, 0);
    __syncthreads();
  }
#undef STAGE

  const int q = lane >> 4;
  const int c16 = lane & 15;
  const int rowbase = pr * 128 + wr * 64;
  const int colbase = pc * 128 + wc * 64;
  const int st = colbase >> 6;

  float invn[4];
  #pragma unroll
  for (int n4 = 0; n4 < 4; ++n4) invn[n4] = invcf[colbase + n4 * 16 + c16];

  #pragma unroll
  for (int m = 0; m < 4; ++m) {
    #pragma unroll
    for (int r = 0; r < 4; ++r) {
      const int row = rowbase + m * 16 + q * 4 + r;
      float sv[4];
      #pragma unroll
      for (int n4 = 0; n4 < 4; ++n4) sv[n4] = acc[m][n4][r] * invn[n4];

      float t1 = sv[0]; int i1 = colbase + c16;
      #pragma unroll
      for (int n4 = 1; n4 < 4; ++n4) {
        const int idx = colbase + n4 * 16 + c16;
        if (sv[n4] > t1) { t1 = sv[n4]; i1 = idx; }
      }
      #pragma unroll
      for (int msk = 1; msk < 16; msk <<= 1) {
        float os = __shfl_xor(t1, msk); int oi = __shfl_xor(i1, msk);
        if (os > t1 || (os == t1 && oi < i1)) { t1 = os; i1 = oi; }
      }

      float t2 = -3.4e38f; int i2 = 0x7fffffff;
      #pragma unroll
      for (int n4 = 0; n4 < 4; ++n4) {
        const int idx = colbase + n4 * 16 + c16;
        if (idx != i1 && sv[n4] > t2) { t2 = sv[n4]; i2 = idx; }
      }
      #pragma unroll
      for (int msk = 1; msk < 16; msk <<= 1) {
        float os = __shfl_xor(t2, msk); int oi = __shfl_xor(i2, msk);
        if (os > t2 || (os == t2 && oi < i2)) { t2 = os; i2 = oi; }
      }

      float t3 = -3.4e38f;
      #pragma unroll
      for (int n4 = 0; n4 < 4; ++n4) {
        const int idx = colbase + n4 * 16 + c16;
        if (idx != i1 && idx != i2 && sv[n4] > t3) t3 = sv[n4];
      }
      #pragma unroll
      for (int msk = 1; msk < 16; msk <<= 1)
        t3 = fmaxf(t3, __shfl_xor(t3, msk));

      if (c16 == 0) {
        pcand[(size_t)row * 16 + st] = make_float4(t1, __int_as_float(i1), t2, __int_as_float(i2));
        pt3[(size_t)row * 16 + st] = __float_as_int(t3);
      }
    }
  }
}

// ------ fused select+write: one wave per row ------
__global__ __launch_bounds__(256) void k_selwrite(const float* __restrict__ h,
                                                  const float* __restrict__ cb,
                                                  const float* __restrict__ cbn,
                                                  const double* __restrict__ invcd,
                                                  const double* __restrict__ hnormd,
                                                  const float* __restrict__ hnormf,
                                                  const float4* __restrict__ pcand,
                                                  const int* __restrict__ pt3,
                                                  float* __restrict__ out_q,
                                                  float* __restrict__ out_ct,
                                                  float* __restrict__ out_ch,
                                                  float* __restrict__ out_cq,
                                                  float* __restrict__ out_idx,
                                                  double* __restrict__ lsum) {
  const int lane = threadIdx.x & 63;
  const int row = blockIdx.x * 4 + (threadIdx.x >> 6);

  float4 pc4 = make_float4(-3.4e38f, 0.0f, -3.4e38f, 0.0f);
  float t3 = -3.4e38f;
  if (lane < 16) {
    pc4 = pcand[(size_t)row * 16 + lane];
    t3 = __int_as_float(pt3[(size_t)row * 16 + lane]);
  }
  float best = pc4.x;
  #pragma unroll
  for (int m = 1; m < 64; m <<= 1) best = fmaxf(best, __shfl_xor(best, m));
  const float thr = best - MARGIN_COEF * hnormf[row];

  const unsigned long long m1 = __ballot(pc4.x >= thr);
  const unsigned long long m2 = __ballot(pc4.z >= thr);
  const unsigned long long mr = __ballot(t3 >= thr);   // ~never fires

  const float* hrow = h + (size_t)row * DDIM;
  const f32x4 h0 = *(const f32x4*)(hrow + lane * 4);
  const f32x4 h1 = *(const f32x4*)(hrow + 256 + lane * 4);

  double bs = -1e300; int bi = 0x7fffffff;
  const int i1 = __float_as_int(pc4.y);
  const int i2 = __float_as_int(pc4.w);

  #define RESCORE(codeexpr)                                                   \
    {                                                                         \
      const int code = (codeexpr);                                            \
      const float* cp = cb + (size_t)code * DDIM;                             \
      const f32x4 c0 = *(const f32x4*)(cp + lane * 4);                        \
      const f32x4 c1 = *(const f32x4*)(cp + 256 + lane * 4);                  \
      double p = (double)h0.x * c0.x + (double)h0.y * c0.y                    \
               + (double)h0.z * c0.z + (double)h0.w * c0.w                    \
               + (double)h1.x * c1.x + (double)h1.y * c1.y                    \
               + (double)h1.z * c1.z + (double)h1.w * c1.w;                   \
      _Pragma("unroll")                                                       \
      for (int m = 1; m < 64; m <<= 1) p += __shfl_xor(p, m);                 \
      const double sc = p * invcd[code];                                      \
      if (sc > bs || (sc == bs && code < bi)) { bs = sc; bi = code; }         \
    }

  for (unsigned long long mm = m1; mm; mm &= mm - 1)
    RESCORE(__shfl(i1, __builtin_ctzll(mm)));
  for (unsigned long long mm = m2; mm; mm &= mm - 1)
    RESCORE(__shfl(i2, __builtin_ctzll(mm)));
  for (unsigned long long mm = mr; mm; mm &= mm - 1) {
    const int st = __builtin_ctzll(mm);
    for (int j = 0; j < 64; ++j) RESCORE(st * 64 + j);
  }
  #undef RESCORE

  if (lane == 0) out_idx[row] = (float)bi;

  {
    float* qrow = out_q + (size_t)row * KCODE;
    #pragma unroll
    for (int p = 0; p < 4; ++p) {
      const int col = p * 256 + lane * 4;
      f32x4 qv;
      qv.x = (col + 0 == bi) ? 1.0f : 0.0f;
      qv.y = (col + 1 == bi) ? 1.0f : 0.0f;
      qv.z = (col + 2 == bi) ? 1.0f : 0.0f;
      qv.w = (col + 3 == bi) ? 1.0f : 0.0f;
      __builtin_nontemporal_store(qv, (f32x4*)(qrow + col));
    }
  }

  const double ih = 1.0 / fmax(hnormd[row], 1e-6);
  const float* crow = cbn + (size_t)bi * DDIM;
  const f32x4 c0 = *(const f32x4*)(crow + lane * 4);
  const f32x4 c1 = *(const f32x4*)(crow + 256 + lane * 4);

  const size_t ro0 = (size_t)row * DDIM + lane * 4;
  const size_t ro1 = ro0 + 256;
  __builtin_nontemporal_store(c0, (f32x4*)(out_ct + ro0));
  __builtin_nontemporal_store(c1, (f32x4*)(out_ct + ro1));
  __builtin_nontemporal_store(c0, (f32x4*)(out_ch + ro0));
  __builtin_nontemporal_store(c1, (f32x4*)(out_ch + ro1));
  __builtin_nontemporal_store(c0, (f32x4*)(out_cq + ro0));
  __builtin_nontemporal_store(c1, (f32x4*)(out_cq + ro1));

  double ls = 0.0, e;
  e = (double)h0.x * ih - (double)c0.x; ls += e * e;
  e = (double)h0.y * ih - (double)c0.y; ls += e * e;
  e = (double)h0.z * ih - (double)c0.z; ls += e * e;
  e = (double)h0.w * ih - (double)c0.w; ls += e * e;
  e = (double)h1.x * ih - (double)c1.x; ls += e * e;
  e = (double)h1.y * ih - (double)c1.y; ls += e * e;
  e = (double)h1.z * ih - (double)c1.z; ls += e * e;
  e = (double)h1.w * ih - (double)c1.w; ls += e * e;
  #pragma unroll
  for (int m = 1; m < 64; m <<= 1) ls += __shfl_xor(ls, m);
  if (lane == 0) lsum[row] = ls;
}

__global__ __launch_bounds__(256) void k_loss(const double* __restrict__ lsum,
                                              float* __restrict__ out_loss) {
  const int tx = threadIdx.x;
  double s = 0.0;
  for (int i = tx; i < NROWS; i += 256) s += lsum[i];
  #pragma unroll
  for (int m = 1; m < 64; m <<= 1) s += __shfl_xor(s, m);
  __shared__ double sh[4];
  if ((tx & 63) == 0) sh[tx >> 6] = s;
  __syncthreads();
  if (tx == 0)
    out_loss[0] = (float)(1.25 * (sh[0] + sh[1] + sh[2] + sh[3]) / ((double)NROWS * (double)DDIM));
}

extern "C" void kernel_launch(void* const* d_in, const int* in_sizes, int n_in,
                              void* d_out, int out_size, void* d_ws, size_t ws_size,
                              hipStream_t stream) {
  const float* h = (const float*)d_in[0];
  const float* cb = (const float*)d_in[1];

  float* out = (float*)d_out;
  float* out_q    = out;
  float* out_ct   = out + 33554432;
  float* out_ch   = out + 50331648;
  float* out_cq   = out + 67108864;
  float* out_loss = out + 83886080;
  float* out_idx  = out + 83886081;

  char* ws = (char*)d_ws;
  unsigned short* AThi = (unsigned short*)(ws);               // 32 MB
  unsigned short* BThi = (unsigned short*)(ws + 33554432);    // 1 MB
  double* invcd  = (double*)(ws + 34603008);                  // 8 KB
  float*  invcf  = (float*)(ws + 34611200);                   // 4 KB
  float*  hnormf = (float*)(ws + 34615296);                   // 128 KB
  float*  cbnrmf = (float*)(ws + 34746368);                   // 4 KB (sink)
  float*  cbn    = (float*)(ws + 34750464);                   // 2 MB
  float4* pcand  = (float4*)(ws + 36847616);                  // 8 MB
  int*    pt3    = (int*)(ws + 45236224);                     // 2 MB
  double* lsum   = (double*)(ws + 47333376);                  // 256 KB
  double* hnormd = (double*)(ws + 47595520);                  // 256 KB
  double* cbnrmd = (double*)(ws + 47857664);                  // 8 KB (sink)

  k_invc<<<KCODE / 4, 256, 0, stream>>>(cb, invcd, invcf, cbn);
  k_prep<<<NROWS / 16, 256, 0, stream>>>(h, AThi, hnormf, hnormd);
  k_prep<<<KCODE / 16, 256, 0, stream>>>(cb, BThi, cbnrmf, cbnrmd);
  k_mfma<<<2048, 256, 0, stream>>>(AThi, BThi, invcf, hnormf, pcand, pt3);
  k_selwrite<<<NROWS / 4, 256, 0, stream>>>(h, cb, cbn, invcd, hnormd, hnormf,
                                            pcand, pt3,
                                            out_q, out_ct, out_ch, out_cq,
                                            out_idx, lsum);
  k_loss<<<1, 256, 0, stream>>>(lsum, out_loss);
}